// Round 14
// baseline (107.585 us; speedup 1.0000x reference)
//
#include <hip/hip_runtime.h>
#include <hip/hip_bf16.h>

#define BATCH 16
#define CDIM 256
#define NDIM 2048
#define HDIM 128
#define KVB 64
#define NT (NDIM / KVB)

typedef __bf16 bf16;
typedef float f32x4 __attribute__((ext_vector_type(4)));
typedef float f32x16 __attribute__((ext_vector_type(16)));
typedef bf16 bf16x8 __attribute__((ext_vector_type(8)));
typedef unsigned int u32x4 __attribute__((ext_vector_type(4)));
typedef unsigned int u32x2 __attribute__((ext_vector_type(2)));

#define LOG2E 1.4426950408889634f

__device__ __forceinline__ int swz512(int row, int colbyte) {
  return row * 512 + (colbyte ^ ((row & 15) << 4));
}
__device__ __forceinline__ int swz256(int row, int colbyte) {
  return row * 256 + (colbyte ^ ((row & 7) << 4));
}

__device__ __forceinline__ f32x4 mfma16(bf16x8 a, bf16x8 b, f32x4 c) {
  return __builtin_amdgcn_mfma_f32_16x16x32_bf16(a, b, c, 0, 0, 0);
}
__device__ __forceinline__ f32x16 mfma32(bf16x8 a, bf16x8 b, f32x16 c) {
  return __builtin_amdgcn_mfma_f32_32x32x16_bf16(a, b, c, 0, 0, 0);
}

__device__ __forceinline__ unsigned cvtpk(float lo, float hi) {
  unsigned r;
  asm("v_cvt_pk_bf16_f32 %0, %1, %2" : "=v"(r) : "v"(lo), "v"(hi));
  return r;
}
__device__ __forceinline__ void pswap(unsigned &a, unsigned &b) {
  asm volatile("v_permlane32_swap_b32 %0, %1" : "+v"(a), "+v"(b));
}

__device__ __forceinline__ void gload16(const bf16* g, char* l) {
  __builtin_amdgcn_global_load_lds(
      (const __attribute__((address_space(1))) void*)g,
      (__attribute__((address_space(3))) void*)l, 16, 0, 0);
}

__device__ __forceinline__ bf16x8 cvt8(float4 a, float4 b) {
  bf16x8 o;
  o[0] = (bf16)a.x; o[1] = (bf16)a.y; o[2] = (bf16)a.z; o[3] = (bf16)a.w;
  o[4] = (bf16)b.x; o[5] = (bf16)b.y; o[6] = (bf16)b.z; o[7] = (bf16)b.w;
  return o;
}

// ---------------------------------------------------------------------------
// Kernel 0: pack Wq/Wk/Wv -> bf16 row-major Wpk[p][128 h][256 c]. (frozen)
// ---------------------------------------------------------------------------
__global__ __launch_bounds__(256) void k0_pack(
    const float* __restrict__ Wq, const float* __restrict__ Wk,
    const float* __restrict__ Wv, bf16* __restrict__ Wpk) {
  int g = blockIdx.x * 256 + threadIdx.x;  // 0..12287
  int p = g >> 12;
  int e = (g & 4095) * 8;
  const float* W = (p == 0) ? Wq : (p == 1 ? Wk : Wv);
  float4 v0 = *reinterpret_cast<const float4*>(W + e);
  float4 v1 = *reinterpret_cast<const float4*>(W + e + 4);
  *reinterpret_cast<bf16x8*>(Wpk + p * 32768 + e) = cvt8(v0, v1);
}

// ---------------------------------------------------------------------------
// Kernel 1: fused QKV projection (frozen from R11; ~at HBM floor).
// ---------------------------------------------------------------------------
__global__ __launch_bounds__(256) void k1_qkv(
    const float* __restrict__ x, const bf16* __restrict__ Wpk,
    const float* __restrict__ bq, const float* __restrict__ bk,
    const float* __restrict__ bv,
    bf16* __restrict__ Qo, bf16* __restrict__ Ko, bf16* __restrict__ Vo) {
  __shared__ char lds_[65536];
  char* xT = lds_;
  char* wb0 = lds_ + 32768;
  char* wb1 = lds_ + 49152;

  const int t = threadIdx.x;
  const int l = t & 63;
  const int w = t >> 6;
  const int q = (l >> 4) & 3;
  const int b = blockIdx.x >> 5;
  const int n0 = (blockIdx.x & 31) * 64;

  const int lane_off = (l >> 3) * 256 + (((l & 7) ^ (l >> 3)) * 8);

#pragma unroll
  for (int i = 0; i < 4; ++i)
    gload16(Wpk + i * 8192 + w * 2048 + lane_off, wb0 + i * 4096 + w * 1024);

#pragma unroll
  for (int p = 0; p < 16; ++p) {
    int c = w * 64 + p * 4 + q;
    float4 v = *reinterpret_cast<const float4*>(
        x + (size_t)(b * CDIM + c) * NDIM + n0 + (l & 15) * 4);
    float t0 = __shfl_xor(v.x, 16), t1 = __shfl_xor(v.y, 16);
    float t2 = __shfl_xor(v.z, 16), t3 = __shfl_xor(v.w, 16);
    float4 wv;
    if ((q & 1) == 0) wv = make_float4(v.x, t0, v.z, t2);
    else              wv = make_float4(t1, v.y, t3, v.w);
    float s0 = __shfl_xor(wv.x, 32), s1 = __shfl_xor(wv.y, 32);
    float s2 = __shfl_xor(wv.z, 32), s3 = __shfl_xor(wv.w, 32);
    float4 z;
    if ((q & 2) == 0) z = make_float4(wv.x, wv.y, s0, s1);
    else              z = make_float4(s2, s3, wv.z, wv.w);
    u32x2 pk = {cvtpk(z.x, z.y), cvtpk(z.z, z.w)};
    int n = (l & 15) * 4 + q;
    int slot = w * 8 + (p >> 1);
    *reinterpret_cast<u32x2*>(
        xT + n * 512 + ((slot ^ (n & 15)) * 16 + (p & 1) * 8)) = pk;
  }
  asm volatile("s_waitcnt lgkmcnt(0)" ::: "memory");

  f32x4 acc[8];
  const float* bias_p[3] = {bq, bk, bv};

#pragma unroll 1
  for (int r = 0; r < 12; ++r) {
    const int p = r >> 2, kq = r & 3;
    char* wb = (r & 1) ? wb1 : wb0;
    if ((r & 3) == 0) {
#pragma unroll
      for (int i = 0; i < 8; ++i) acc[i] = f32x4{0.f, 0.f, 0.f, 0.f};
    }
    if (r + 1 < 12) {
      const int p1 = (r + 1) >> 2, kq1 = (r + 1) & 3;
      char* nwb = (r & 1) ? wb0 : wb1;
      const bf16* src = Wpk + p1 * 32768 + kq1 * 64 + w * 2048 + lane_off;
#pragma unroll
      for (int i = 0; i < 4; ++i)
        gload16(src + i * 8192, nwb + i * 4096 + w * 1024);
      asm volatile("s_waitcnt vmcnt(4)" ::: "memory");
    } else {
      asm volatile("s_waitcnt vmcnt(0)" ::: "memory");
    }
    __builtin_amdgcn_s_barrier();

    if (p < 2) {
#pragma unroll
      for (int ks = 0; ks < 2; ++ks) {
        int cb = kq * 128 + ks * 64 + (l >> 4) * 16;
        bf16x8 a = *reinterpret_cast<const bf16x8*>(
            xT + swz512(w * 16 + (l & 15), cb));
        int slot = ((ks * 4 + (l >> 4)) ^ (l & 7)) * 16;
#pragma unroll
        for (int nf = 0; nf < 8; ++nf) {
          bf16x8 bb = *reinterpret_cast<const bf16x8*>(
              wb + (nf * 16 + (l & 15)) * 128 + slot);
          acc[nf] = mfma16(a, bb, acc[nf]);
        }
      }
    } else {
#pragma unroll
      for (int ks = 0; ks < 2; ++ks) {
        int slot = ((ks * 4 + (l >> 4)) ^ (l & 7)) * 16;
        bf16x8 a0 = *reinterpret_cast<const bf16x8*>(
            wb + (w * 32 + (l & 15)) * 128 + slot);
        bf16x8 a1 = *reinterpret_cast<const bf16x8*>(
            wb + (w * 32 + 16 + (l & 15)) * 128 + slot);
        int cb = kq * 128 + ks * 64 + (l >> 4) * 16;
#pragma unroll
        for (int nf4 = 0; nf4 < 4; ++nf4) {
          bf16x8 bx = *reinterpret_cast<const bf16x8*>(
              xT + swz512(nf4 * 16 + (l & 15), cb));
          acc[nf4] = mfma16(a0, bx, acc[nf4]);
          acc[4 + nf4] = mfma16(a1, bx, acc[4 + nf4]);
        }
      }
    }

    if ((r & 3) == 3) {
      if (p < 2) {
        bf16* dst = (p == 0) ? Qo : Ko;
        const float scale = (p == 0) ? LOG2E : 1.0f;
#pragma unroll
        for (int nf = 0; nf < 8; ++nf) {
          float bias = bias_p[p][nf * 16 + (l & 15)];
#pragma unroll
          for (int rr = 0; rr < 4; ++rr) {
            int n = n0 + w * 16 + (l >> 4) * 4 + rr;
            int h = nf * 16 + (l & 15);
            dst[(size_t)(b * NDIM + n) * HDIM + h] =
                (bf16)((acc[nf][rr] + bias) * scale);
          }
        }
      } else {
#pragma unroll
        for (int mf = 0; mf < 2; ++mf)
#pragma unroll
          for (int nf4 = 0; nf4 < 4; ++nf4)
#pragma unroll
            for (int rr = 0; rr < 4; ++rr) {
              int h = w * 32 + mf * 16 + (l >> 4) * 4 + rr;
              int n = n0 + nf4 * 16 + (l & 15);
              Vo[(size_t)(b * HDIM + h) * NDIM + n] =
                  (bf16)(acc[mf * 4 + nf4][rr] + bv[h]);
            }
      }
    }
    __builtin_amdgcn_s_barrier();
  }
}

// ---------------------------------------------------------------------------
// Kernel 2: flash attention, 1-tile software pipeline + dual-accumulator
// QK^T (dep chain 8 -> 4+add). __launch_bounds__(256,1): occupancy is
// LDS-capped at 2 blocks/CU regardless, so the relaxed bound only lifts the
// VGPR clamp (R13's (256,2) clamped at 128 and spilled 5.6 MB).
// ---------------------------------------------------------------------------
__global__ __launch_bounds__(256, 1) void k2_attn(
    const bf16* __restrict__ Q, const bf16* __restrict__ K,
    const bf16* __restrict__ V, bf16* __restrict__ O) {
  extern __shared__ char lds[];
  // buf0 @0, buf1 @32768; each: Kt [64 kpos][256B] @0, Vt [128 d][128B] @16384

  const int t = threadIdx.x;
  const int l = t & 63;
  const int w = t >> 6;     // 0..3
  const int wm = w & 1;     // q-subtile (32 rows)
  const int wk = w >> 1;    // kpos half (32 kpos)
  const int hi = l >> 5;
  const int c31 = l & 31;

  const int pid = blockIdx.x;
  const int b = (pid & 7) * 2 + ((pid >> 3) >> 5);
  const int q0 = ((pid >> 3) & 31) * 64;

  bf16x8 qf[8];
  {
    const bf16* qb = Q + ((size_t)b * NDIM + q0 + wm * 32 + c31) * HDIM + hi * 8;
#pragma unroll
    for (int cs = 0; cs < 8; ++cs)
      qf[cs] = *reinterpret_cast<const bf16x8*>(qb + cs * 16);
  }

  unsigned offK[4], offV[4];
  {
    const int krow_s = w * 16 + (l >> 4);
    const int kslot = l & 15;
#pragma unroll
    for (int i = 0; i < 4; ++i) {
      int r = krow_s + i * 4;
      offK[i] = (unsigned)((b * NDIM + r) * HDIM + (kslot ^ (r & 15)) * 8);
    }
    const int vrow = w * 32 + (l >> 3);
    const int vslot = l & 7;
#pragma unroll
    for (int i = 0; i < 4; ++i) {
      int r = vrow + i * 8;
      offV[i] = (unsigned)((b * HDIM + r) * NDIM + (vslot ^ (r & 7)) * 8);
    }
  }
  const int kbase = w * 4096;
  const int vbase = 16384 + w * 4096;

  f32x16 oacc[4];
#pragma unroll
  for (int dg = 0; dg < 4; ++dg)
#pragma unroll
    for (int r = 0; r < 16; ++r) oacc[dg][r] = 0.f;
  float l_run = 0.f;

  const int krow = wk * 32 + c31;
  const int rxk = krow & 15;
  const int rxv = c31 & 7;

  auto stage_to = [&](char* nbuf) {
#pragma unroll
    for (int i = 0; i < 4; ++i) {
      offK[i] += (unsigned)(KVB * HDIM);
      gload16(K + offK[i], nbuf + kbase + i * 1024);
    }
#pragma unroll
    for (int i = 0; i < 4; ++i) {
      offV[i] += (unsigned)KVB;
      gload16(V + offV[i], nbuf + vbase + i * 1024);
    }
  };
  // Dual-accumulator QK^T: even chunks -> s0, odd -> s1 (chain depth 4).
  auto qkt = [&](const char* buf, f32x16& s) {
    f32x16 s0, s1;
#pragma unroll
    for (int r = 0; r < 16; ++r) { s0[r] = 0.f; s1[r] = 0.f; }
    const char* kr = buf + krow * 256;
    __builtin_amdgcn_s_setprio(1);
#pragma unroll
    for (int cs = 0; cs < 8; cs += 2) {
      bf16x8 kf0 = *reinterpret_cast<const bf16x8*>(
          kr + (((cs * 2 + hi) ^ rxk) * 16));
      s0 = mfma32(kf0, qf[cs], s0);
      bf16x8 kf1 = *reinterpret_cast<const bf16x8*>(
          kr + ((((cs + 1) * 2 + hi) ^ rxk) * 16));
      s1 = mfma32(kf1, qf[cs + 1], s1);
    }
    __builtin_amdgcn_s_setprio(0);
#pragma unroll
    for (int r = 0; r < 16; ++r) s[r] = s0[r] + s1[r];
  };
  auto ldv = [&](const char* buf, bf16x8 (&vf)[8]) {
    const char* Vt = buf + 16384;
#pragma unroll
    for (int dg = 0; dg < 4; ++dg) {
      const char* vr = Vt + (dg * 32 + c31) * 128;
      vf[2 * dg + 0] = *reinterpret_cast<const bf16x8*>(
          vr + (((wk * 4 + 0 + hi) ^ rxv) * 16));
      vf[2 * dg + 1] = *reinterpret_cast<const bf16x8*>(
          vr + (((wk * 4 + 2 + hi) ^ rxv) * 16));
    }
  };
  auto smpv = [&](f32x16& s, bf16x8 (&vf)[8]) {
#pragma unroll
    for (int r = 0; r < 16; ++r) s[r] = __builtin_amdgcn_exp2f(s[r]);
    {
      float a0 = s[0] + s[1], a1 = s[2] + s[3], a2 = s[4] + s[5], a3 = s[6] + s[7];
      float a4 = s[8] + s[9], a5 = s[10] + s[11], a6 = s[12] + s[13], a7 = s[14] + s[15];
      float b0 = a0 + a1, b1 = a2 + a3, b2 = a4 + a5, b3 = a6 + a7;
      l_run += (b0 + b1) + (b2 + b3);
    }
    unsigned w0 = cvtpk(s[0], s[1]);
    unsigned w1 = cvtpk(s[2], s[3]);
    unsigned w2 = cvtpk(s[4], s[5]);
    unsigned w3 = cvtpk(s[6], s[7]);
    unsigned w4 = cvtpk(s[8], s[9]);
    unsigned w5 = cvtpk(s[10], s[11]);
    unsigned w6 = cvtpk(s[12], s[13]);
    unsigned w7 = cvtpk(s[14], s[15]);
    pswap(w0, w2); pswap(w1, w3); pswap(w4, w6); pswap(w5, w7);
    u32x4 pw0 = {w0, w1, w2, w3};
    u32x4 pw1 = {w4, w5, w6, w7};
    bf16x8 pa0 = __builtin_bit_cast(bf16x8, pw0);
    bf16x8 pa1 = __builtin_bit_cast(bf16x8, pw1);
    __builtin_amdgcn_s_setprio(1);
#pragma unroll
    for (int dg = 0; dg < 4; ++dg) {
      oacc[dg] = mfma32(pa0, vf[2 * dg + 0], oacc[dg]);
      oacc[dg] = mfma32(pa1, vf[2 * dg + 1], oacc[dg]);
    }
    __builtin_amdgcn_s_setprio(0);
  };

  f32x16 sA, sB;
  bf16x8 vfA[8], vfB[8];
  char* const buf0 = lds;
  char* const buf1 = lds + 32768;

  // ---- prologue: stage tile0, then QKT(0); tile1 issued behind the barrier.
#pragma unroll
  for (int i = 0; i < 4; ++i) gload16(K + offK[i], buf0 + kbase + i * 1024);
#pragma unroll
  for (int i = 0; i < 4; ++i) gload16(V + offV[i], buf0 + vbase + i * 1024);
  asm volatile("s_waitcnt vmcnt(0)" ::: "memory");
  __builtin_amdgcn_s_barrier();
  stage_to(buf1);                 // tile 1
  ldv(buf0, vfA);
  qkt(buf0, sA);

  // ---- steady state: bodies kt=1..30 in pairs, then kt=31.
#pragma unroll 1
  for (int base = 1; base < NT - 1; base += 2) {
    // body(odd kt): compute buf1, stage -> buf0
    asm volatile("s_waitcnt vmcnt(0)" ::: "memory");
    __builtin_amdgcn_s_barrier();
    stage_to(buf0);               // tile base+1
    ldv(buf1, vfB);
    qkt(buf1, sB);
    smpv(sA, vfA);                // overlaps QKT's MFMAs (independent)
    // body(even kt): compute buf0, stage -> buf1
    asm volatile("s_waitcnt vmcnt(0)" ::: "memory");
    __builtin_amdgcn_s_barrier();
    stage_to(buf1);               // tile base+2 (max 31)
    ldv(buf0, vfA);
    qkt(buf0, sA);
    smpv(sB, vfB);
  }
  // body(kt=31): compute buf1, no stage
  asm volatile("s_waitcnt vmcnt(0)" ::: "memory");
  __builtin_amdgcn_s_barrier();
  ldv(buf1, vfB);
  qkt(buf1, sB);
  smpv(sA, vfA);
  // drain
  smpv(sB, vfB);

  // ---- split-k-2 merge (wk pairs). Tile buffers dead; reuse LDS.
  __syncthreads();  // all waves done with tile buffers
  l_run += __shfl_xor(l_run, 32);
  float* O1 = (float*)lds;
  float* L1 = (float*)(lds + 32768);
  if (wk == 1) {
#pragma unroll
    for (int dg = 0; dg < 4; ++dg)
#pragma unroll
      for (int r = 0; r < 16; ++r)
        O1[wm * 4096 + (dg * 16 + r) * 64 + l] = oacc[dg][r];
    if (l < 32) L1[wm * 32 + c31] = l_run;
  }
  __syncthreads();
  if (wk == 0) {
    float linv = 1.0f / (l_run + L1[wm * 32 + c31]);
    int ibits = __builtin_bit_cast(int, linv);
#pragma unroll
    for (int dg = 0; dg < 4; ++dg) {
      int h = dg * 32 + c31;
#pragma unroll
      for (int r = 0; r < 16; ++r) {
        int crow = (r & 3) + 8 * (r >> 2) + 4 * hi;
        float fr = __builtin_bit_cast(
            float, __builtin_amdgcn_ds_bpermute(crow * 4, ibits));
        float val = (oacc[dg][r] + O1[wm * 4096 + (dg * 16 + r) * 64 + l]) * fr;
        int n = q0 + wm * 32 + crow;
        O[((size_t)b * NDIM + n) * HDIM + h] = (bf16)val;
      }
    }
  }
}

// ---------------------------------------------------------------------------
// Kernel 3: out = Wf @ O + bf + x (frozen; ~at HBM floor)
// ---------------------------------------------------------------------------
__global__ __launch_bounds__(256) void k3_proj(
    const bf16* __restrict__ O, const float* __restrict__ Wf,
    const float* __restrict__ bfv, const float* __restrict__ x,
    float* __restrict__ out) {
  __shared__ char lds[49152];
  char* Wt = lds;
  char* Ot = lds + 32768;

  const int t = threadIdx.x;
  const int l = t & 63;
  const int w = t >> 6;
  const int b = blockIdx.x >> 5;
  const int n0 = (blockIdx.x & 31) * 64;

#pragma unroll
  for (int pass = 0; pass < 4; ++pass) {
    int n = pass * 16 + (t >> 4);
    int hq = t & 15;
    uint4 d = *reinterpret_cast<const uint4*>(
        O + (size_t)(b * NDIM + n0 + n) * HDIM + hq * 8);
    *reinterpret_cast<uint4*>(Ot + swz256(n, hq * 16)) = d;
  }

#pragma unroll 1
  for (int ch = 0; ch < 2; ++ch) {
    __syncthreads();
#pragma unroll
    for (int pass = 0; pass < 8; ++pass) {
      int cl = pass * 16 + (t >> 4);
      int hq = t & 15;
      const float* src = Wf + (size_t)(ch * 128 + cl) * HDIM + hq * 8;
      float4 v0 = *reinterpret_cast<const float4*>(src);
      float4 v1 = *reinterpret_cast<const float4*>(src + 4);
      *reinterpret_cast<bf16x8*>(Wt + swz256(cl, hq * 16)) = cvt8(v0, v1);
    }
    __syncthreads();

    f32x4 acc[2][4];
#pragma unroll
    for (int i = 0; i < 2; ++i)
#pragma unroll
      for (int j = 0; j < 4; ++j) acc[i][j] = f32x4{0.f, 0.f, 0.f, 0.f};

#pragma unroll
    for (int ks = 0; ks < 4; ++ks) {
      int cb = ks * 64 + (l >> 4) * 16;
      bf16x8 a0 = *reinterpret_cast<const bf16x8*>(
          Wt + swz256(w * 32 + (l & 15), cb));
      bf16x8 a1 = *reinterpret_cast<const bf16x8*>(
          Wt + swz256(w * 32 + 16 + (l & 15), cb));
#pragma unroll
      for (int nf = 0; nf < 4; ++nf) {
        bf16x8 bb = *reinterpret_cast<const bf16x8*>(
            Ot + swz256(nf * 16 + (l & 15), cb));
        acc[0][nf] = mfma16(a0, bb, acc[0][nf]);
        acc[1][nf] = mfma16(a1, bb, acc[1][nf]);
      }
    }

#pragma unroll
    for (int mf = 0; mf < 2; ++mf)
#pragma unroll
      for (int nf = 0; nf < 4; ++nf)
#pragma unroll
        for (int r = 0; r < 4; ++r) {
          int c = ch * 128 + w * 32 + mf * 16 + (l >> 4) * 4 + r;
          int n = n0 + nf * 16 + (l & 15);
          size_t idx = (size_t)(b * CDIM + c) * NDIM + n;
          out[idx] = acc[mf][nf][r] + bfv[c] + x[idx];
        }
  }
}

extern "C" void kernel_launch(void* const* d_in, const int* in_sizes, int n_in,
                              void* d_out, int out_size, void* d_ws,
                              size_t ws_size, hipStream_t stream) {
  (void)in_sizes; (void)n_in;
  const float* x = (const float*)d_in[0];
  const float* Wq = (const float*)d_in[1];
  const float* bq = (const float*)d_in[2];
  const float* Wk = (const float*)d_in[3];
  const float* bk = (const float*)d_in[4];
  const float* Wv = (const float*)d_in[5];
  const float* bv = (const float*)d_in[6];
  const float* Wf = (const float*)d_in[7];
  const float* bfv = (const float*)d_in[8];
  float* out = (float*)d_out;

  if (ws_size < (24u << 20)) return;
  char* ws = (char*)d_ws;
  bf16* Qb = (bf16*)(ws);                  // 8 MB [B][N][H]; reused as O
  bf16* Kb = (bf16*)(ws + (8u << 20));     // 8 MB [B][N][H]
  bf16* Vb = (bf16*)(ws + (16u << 20));    // 8 MB [B][H][N]

  const size_t out_bytes = (size_t)out_size * 4;
  bf16* Wpk = (bf16*)((char*)d_out + out_bytes - 196608);

  const unsigned k2_lds = 65536;
  hipFuncSetAttribute(reinterpret_cast<const void*>(k2_attn),
                      hipFuncAttributeMaxDynamicSharedMemorySize, (int)k2_lds);

  k0_pack<<<48, 256, 0, stream>>>(Wq, Wk, Wv, Wpk);
  k1_qkv<<<512, 256, 0, stream>>>(x, Wpk, bq, bk, bv, Qb, Kb, Vb);
  k2_attn<<<512, 256, k2_lds, stream>>>(Qb, Kb, Vb, Qb);
  k3_proj<<<512, 256, 0, stream>>>(Qb, Wf, bfv, x, out);
}

// Round 15
// 89.789 us; speedup vs baseline: 1.1982x; 1.1982x over previous
//
#include <hip/hip_runtime.h>
#include <hip/hip_bf16.h>

#define BATCH 16
#define CDIM 256
#define NDIM 2048
#define HDIM 128
#define KVB 64
#define NT (NDIM / KVB)

typedef __bf16 bf16;
typedef float f32x4 __attribute__((ext_vector_type(4)));
typedef float f32x16 __attribute__((ext_vector_type(16)));
typedef bf16 bf16x8 __attribute__((ext_vector_type(8)));
typedef unsigned int u32x4 __attribute__((ext_vector_type(4)));
typedef unsigned int u32x2 __attribute__((ext_vector_type(2)));

#define LOG2E 1.4426950408889634f

__device__ __forceinline__ int swz512(int row, int colbyte) {
  return row * 512 + (colbyte ^ ((row & 15) << 4));
}
__device__ __forceinline__ int swz256(int row, int colbyte) {
  return row * 256 + (colbyte ^ ((row & 7) << 4));
}

__device__ __forceinline__ f32x4 mfma16(bf16x8 a, bf16x8 b, f32x4 c) {
  return __builtin_amdgcn_mfma_f32_16x16x32_bf16(a, b, c, 0, 0, 0);
}
__device__ __forceinline__ f32x16 mfma32(bf16x8 a, bf16x8 b, f32x16 c) {
  return __builtin_amdgcn_mfma_f32_32x32x16_bf16(a, b, c, 0, 0, 0);
}

__device__ __forceinline__ unsigned cvtpk(float lo, float hi) {
  unsigned r;
  asm("v_cvt_pk_bf16_f32 %0, %1, %2" : "=v"(r) : "v"(lo), "v"(hi));
  return r;
}
__device__ __forceinline__ void pswap(unsigned &a, unsigned &b) {
  asm volatile("v_permlane32_swap_b32 %0, %1" : "+v"(a), "+v"(b));
}

__device__ __forceinline__ void gload16(const bf16* g, char* l) {
  __builtin_amdgcn_global_load_lds(
      (const __attribute__((address_space(1))) void*)g,
      (__attribute__((address_space(3))) void*)l, 16, 0, 0);
}

__device__ __forceinline__ bf16x8 cvt8(float4 a, float4 b) {
  bf16x8 o;
  o[0] = (bf16)a.x; o[1] = (bf16)a.y; o[2] = (bf16)a.z; o[3] = (bf16)a.w;
  o[4] = (bf16)b.x; o[5] = (bf16)b.y; o[6] = (bf16)b.z; o[7] = (bf16)b.w;
  return o;
}

// ---------------------------------------------------------------------------
// Kernel 0: pack Wq/Wk/Wv -> bf16 row-major Wpk[p][128 h][256 c]. (frozen)
// ---------------------------------------------------------------------------
__global__ __launch_bounds__(256) void k0_pack(
    const float* __restrict__ Wq, const float* __restrict__ Wk,
    const float* __restrict__ Wv, bf16* __restrict__ Wpk) {
  int g = blockIdx.x * 256 + threadIdx.x;  // 0..12287
  int p = g >> 12;
  int e = (g & 4095) * 8;
  const float* W = (p == 0) ? Wq : (p == 1 ? Wk : Wv);
  float4 v0 = *reinterpret_cast<const float4*>(W + e);
  float4 v1 = *reinterpret_cast<const float4*>(W + e + 4);
  *reinterpret_cast<bf16x8*>(Wpk + p * 32768 + e) = cvt8(v0, v1);
}

// ---------------------------------------------------------------------------
// Kernel 1: fused QKV projection (frozen from R11; ~at HBM floor).
// ---------------------------------------------------------------------------
__global__ __launch_bounds__(256) void k1_qkv(
    const float* __restrict__ x, const bf16* __restrict__ Wpk,
    const float* __restrict__ bq, const float* __restrict__ bk,
    const float* __restrict__ bv,
    bf16* __restrict__ Qo, bf16* __restrict__ Ko, bf16* __restrict__ Vo) {
  __shared__ char lds_[65536];
  char* xT = lds_;
  char* wb0 = lds_ + 32768;
  char* wb1 = lds_ + 49152;

  const int t = threadIdx.x;
  const int l = t & 63;
  const int w = t >> 6;
  const int q = (l >> 4) & 3;
  const int b = blockIdx.x >> 5;
  const int n0 = (blockIdx.x & 31) * 64;

  const int lane_off = (l >> 3) * 256 + (((l & 7) ^ (l >> 3)) * 8);

#pragma unroll
  for (int i = 0; i < 4; ++i)
    gload16(Wpk + i * 8192 + w * 2048 + lane_off, wb0 + i * 4096 + w * 1024);

#pragma unroll
  for (int p = 0; p < 16; ++p) {
    int c = w * 64 + p * 4 + q;
    float4 v = *reinterpret_cast<const float4*>(
        x + (size_t)(b * CDIM + c) * NDIM + n0 + (l & 15) * 4);
    float t0 = __shfl_xor(v.x, 16), t1 = __shfl_xor(v.y, 16);
    float t2 = __shfl_xor(v.z, 16), t3 = __shfl_xor(v.w, 16);
    float4 wv;
    if ((q & 1) == 0) wv = make_float4(v.x, t0, v.z, t2);
    else              wv = make_float4(t1, v.y, t3, v.w);
    float s0 = __shfl_xor(wv.x, 32), s1 = __shfl_xor(wv.y, 32);
    float s2 = __shfl_xor(wv.z, 32), s3 = __shfl_xor(wv.w, 32);
    float4 z;
    if ((q & 2) == 0) z = make_float4(wv.x, wv.y, s0, s1);
    else              z = make_float4(s2, s3, wv.z, wv.w);
    u32x2 pk = {cvtpk(z.x, z.y), cvtpk(z.z, z.w)};
    int n = (l & 15) * 4 + q;
    int slot = w * 8 + (p >> 1);
    *reinterpret_cast<u32x2*>(
        xT + n * 512 + ((slot ^ (n & 15)) * 16 + (p & 1) * 8)) = pk;
  }
  asm volatile("s_waitcnt lgkmcnt(0)" ::: "memory");

  f32x4 acc[8];
  const float* bias_p[3] = {bq, bk, bv};

#pragma unroll 1
  for (int r = 0; r < 12; ++r) {
    const int p = r >> 2, kq = r & 3;
    char* wb = (r & 1) ? wb1 : wb0;
    if ((r & 3) == 0) {
#pragma unroll
      for (int i = 0; i < 8; ++i) acc[i] = f32x4{0.f, 0.f, 0.f, 0.f};
    }
    if (r + 1 < 12) {
      const int p1 = (r + 1) >> 2, kq1 = (r + 1) & 3;
      char* nwb = (r & 1) ? wb0 : wb1;
      const bf16* src = Wpk + p1 * 32768 + kq1 * 64 + w * 2048 + lane_off;
#pragma unroll
      for (int i = 0; i < 4; ++i)
        gload16(src + i * 8192, nwb + i * 4096 + w * 1024);
      asm volatile("s_waitcnt vmcnt(4)" ::: "memory");
    } else {
      asm volatile("s_waitcnt vmcnt(0)" ::: "memory");
    }
    __builtin_amdgcn_s_barrier();

    if (p < 2) {
#pragma unroll
      for (int ks = 0; ks < 2; ++ks) {
        int cb = kq * 128 + ks * 64 + (l >> 4) * 16;
        bf16x8 a = *reinterpret_cast<const bf16x8*>(
            xT + swz512(w * 16 + (l & 15), cb));
        int slot = ((ks * 4 + (l >> 4)) ^ (l & 7)) * 16;
#pragma unroll
        for (int nf = 0; nf < 8; ++nf) {
          bf16x8 bb = *reinterpret_cast<const bf16x8*>(
              wb + (nf * 16 + (l & 15)) * 128 + slot);
          acc[nf] = mfma16(a, bb, acc[nf]);
        }
      }
    } else {
#pragma unroll
      for (int ks = 0; ks < 2; ++ks) {
        int slot = ((ks * 4 + (l >> 4)) ^ (l & 7)) * 16;
        bf16x8 a0 = *reinterpret_cast<const bf16x8*>(
            wb + (w * 32 + (l & 15)) * 128 + slot);
        bf16x8 a1 = *reinterpret_cast<const bf16x8*>(
            wb + (w * 32 + 16 + (l & 15)) * 128 + slot);
        int cb = kq * 128 + ks * 64 + (l >> 4) * 16;
#pragma unroll
        for (int nf4 = 0; nf4 < 4; ++nf4) {
          bf16x8 bx = *reinterpret_cast<const bf16x8*>(
              xT + swz512(nf4 * 16 + (l & 15), cb));
          acc[nf4] = mfma16(a0, bx, acc[nf4]);
          acc[4 + nf4] = mfma16(a1, bx, acc[4 + nf4]);
        }
      }
    }

    if ((r & 3) == 3) {
      if (p < 2) {
        bf16* dst = (p == 0) ? Qo : Ko;
        const float scale = (p == 0) ? LOG2E : 1.0f;
#pragma unroll
        for (int nf = 0; nf < 8; ++nf) {
          float bias = bias_p[p][nf * 16 + (l & 15)];
#pragma unroll
          for (int rr = 0; rr < 4; ++rr) {
            int n = n0 + w * 16 + (l >> 4) * 4 + rr;
            int h = nf * 16 + (l & 15);
            dst[(size_t)(b * NDIM + n) * HDIM + h] =
                (bf16)((acc[nf][rr] + bias) * scale);
          }
        }
      } else {
#pragma unroll
        for (int mf = 0; mf < 2; ++mf)
#pragma unroll
          for (int nf4 = 0; nf4 < 4; ++nf4)
#pragma unroll
            for (int rr = 0; rr < 4; ++rr) {
              int h = w * 32 + mf * 16 + (l >> 4) * 4 + rr;
              int n = n0 + nf4 * 16 + (l & 15);
              Vo[(size_t)(b * HDIM + h) * NDIM + n] =
                  (bf16)(acc[mf * 4 + nf4][rr] + bv[h]);
            }
      }
    }
    __builtin_amdgcn_s_barrier();
  }
}

// ---------------------------------------------------------------------------
// Kernel 2: flash attention (R12 best config): 1-tile software pipeline,
// exp2-direct softmax (Q pre-scaled), KVB=64 dbuf (2 blocks/CU), counted
// vmcnt staging, in-register P, split-k-2 merge. VGPR 116 @ (256,2) — the
// proven spill-free/occupancy-preserving register budget.
// ---------------------------------------------------------------------------
__global__ __launch_bounds__(256, 2) void k2_attn(
    const bf16* __restrict__ Q, const bf16* __restrict__ K,
    const bf16* __restrict__ V, bf16* __restrict__ O) {
  extern __shared__ char lds[];
  // buf0 @0, buf1 @32768; each: Kt [64 kpos][256B] @0, Vt [128 d][128B] @16384

  const int t = threadIdx.x;
  const int l = t & 63;
  const int w = t >> 6;     // 0..3
  const int wm = w & 1;     // q-subtile (32 rows)
  const int wk = w >> 1;    // kpos half (32 kpos)
  const int hi = l >> 5;
  const int c31 = l & 31;

  const int pid = blockIdx.x;
  const int b = (pid & 7) * 2 + ((pid >> 3) >> 5);
  const int q0 = ((pid >> 3) & 31) * 64;

  bf16x8 qf[8];
  {
    const bf16* qb = Q + ((size_t)b * NDIM + q0 + wm * 32 + c31) * HDIM + hi * 8;
#pragma unroll
    for (int cs = 0; cs < 8; ++cs)
      qf[cs] = *reinterpret_cast<const bf16x8*>(qb + cs * 16);
  }

  unsigned offK[4], offV[4];
  {
    const int krow_s = w * 16 + (l >> 4);
    const int kslot = l & 15;
#pragma unroll
    for (int i = 0; i < 4; ++i) {
      int r = krow_s + i * 4;
      offK[i] = (unsigned)((b * NDIM + r) * HDIM + (kslot ^ (r & 15)) * 8);
    }
    const int vrow = w * 32 + (l >> 3);
    const int vslot = l & 7;
#pragma unroll
    for (int i = 0; i < 4; ++i) {
      int r = vrow + i * 8;
      offV[i] = (unsigned)((b * HDIM + r) * NDIM + (vslot ^ (r & 7)) * 8);
    }
  }
  const int kbase = w * 4096;
  const int vbase = 16384 + w * 4096;

  f32x16 oacc[4];
#pragma unroll
  for (int dg = 0; dg < 4; ++dg)
#pragma unroll
    for (int r = 0; r < 16; ++r) oacc[dg][r] = 0.f;
  float l_run = 0.f;

  const int krow = wk * 32 + c31;
  const int rxk = krow & 15;
  const int rxv = c31 & 7;

  auto stage_to = [&](char* nbuf) {
#pragma unroll
    for (int i = 0; i < 4; ++i) {
      offK[i] += (unsigned)(KVB * HDIM);
      gload16(K + offK[i], nbuf + kbase + i * 1024);
    }
#pragma unroll
    for (int i = 0; i < 4; ++i) {
      offV[i] += (unsigned)KVB;
      gload16(V + offV[i], nbuf + vbase + i * 1024);
    }
  };
  auto qkt = [&](const char* buf, f32x16& s) {
#pragma unroll
    for (int r = 0; r < 16; ++r) s[r] = 0.f;
    const char* kr = buf + krow * 256;
    __builtin_amdgcn_s_setprio(1);
#pragma unroll
    for (int cs = 0; cs < 8; ++cs) {
      bf16x8 kf = *reinterpret_cast<const bf16x8*>(
          kr + (((cs * 2 + hi) ^ rxk) * 16));
      s = mfma32(kf, qf[cs], s);
    }
    __builtin_amdgcn_s_setprio(0);
  };
  auto ldv = [&](const char* buf, bf16x8 (&vf)[8]) {
    const char* Vt = buf + 16384;
#pragma unroll
    for (int dg = 0; dg < 4; ++dg) {
      const char* vr = Vt + (dg * 32 + c31) * 128;
      vf[2 * dg + 0] = *reinterpret_cast<const bf16x8*>(
          vr + (((wk * 4 + 0 + hi) ^ rxv) * 16));
      vf[2 * dg + 1] = *reinterpret_cast<const bf16x8*>(
          vr + (((wk * 4 + 2 + hi) ^ rxv) * 16));
    }
  };
  auto smpv = [&](f32x16& s, bf16x8 (&vf)[8]) {
#pragma unroll
    for (int r = 0; r < 16; ++r) s[r] = __builtin_amdgcn_exp2f(s[r]);
    {
      float a0 = s[0] + s[1], a1 = s[2] + s[3], a2 = s[4] + s[5], a3 = s[6] + s[7];
      float a4 = s[8] + s[9], a5 = s[10] + s[11], a6 = s[12] + s[13], a7 = s[14] + s[15];
      float b0 = a0 + a1, b1 = a2 + a3, b2 = a4 + a5, b3 = a6 + a7;
      l_run += (b0 + b1) + (b2 + b3);
    }
    unsigned w0 = cvtpk(s[0], s[1]);
    unsigned w1 = cvtpk(s[2], s[3]);
    unsigned w2 = cvtpk(s[4], s[5]);
    unsigned w3 = cvtpk(s[6], s[7]);
    unsigned w4 = cvtpk(s[8], s[9]);
    unsigned w5 = cvtpk(s[10], s[11]);
    unsigned w6 = cvtpk(s[12], s[13]);
    unsigned w7 = cvtpk(s[14], s[15]);
    pswap(w0, w2); pswap(w1, w3); pswap(w4, w6); pswap(w5, w7);
    u32x4 pw0 = {w0, w1, w2, w3};
    u32x4 pw1 = {w4, w5, w6, w7};
    bf16x8 pa0 = __builtin_bit_cast(bf16x8, pw0);
    bf16x8 pa1 = __builtin_bit_cast(bf16x8, pw1);
    __builtin_amdgcn_s_setprio(1);
#pragma unroll
    for (int dg = 0; dg < 4; ++dg) {
      oacc[dg] = mfma32(pa0, vf[2 * dg + 0], oacc[dg]);
      oacc[dg] = mfma32(pa1, vf[2 * dg + 1], oacc[dg]);
    }
    __builtin_amdgcn_s_setprio(0);
  };

  f32x16 sA, sB;
  bf16x8 vfA[8], vfB[8];
  char* const buf0 = lds;
  char* const buf1 = lds + 32768;

  // ---- prologue: stage tile0, then QKT(0); tile1 issued behind the barrier.
#pragma unroll
  for (int i = 0; i < 4; ++i) gload16(K + offK[i], buf0 + kbase + i * 1024);
#pragma unroll
  for (int i = 0; i < 4; ++i) gload16(V + offV[i], buf0 + vbase + i * 1024);
  asm volatile("s_waitcnt vmcnt(0)" ::: "memory");
  __builtin_amdgcn_s_barrier();
  stage_to(buf1);                 // tile 1
  qkt(buf0, sA);
  ldv(buf0, vfA);

  // ---- steady state: bodies kt=1..30 in pairs, then kt=31.
#pragma unroll 1
  for (int base = 1; base < NT - 1; base += 2) {
    // body(odd kt): compute buf1, stage -> buf0
    asm volatile("s_waitcnt vmcnt(0)" ::: "memory");
    __builtin_amdgcn_s_barrier();
    stage_to(buf0);               // tile base+1
    qkt(buf1, sB);
    smpv(sA, vfA);                // overlaps QKT's MFMAs (independent)
    ldv(buf1, vfB);
    // body(even kt): compute buf0, stage -> buf1
    asm volatile("s_waitcnt vmcnt(0)" ::: "memory");
    __builtin_amdgcn_s_barrier();
    stage_to(buf1);               // tile base+2 (max 31)
    qkt(buf0, sA);
    smpv(sB, vfB);
    ldv(buf0, vfA);
  }
  // body(kt=31): compute buf1, no stage
  asm volatile("s_waitcnt vmcnt(0)" ::: "memory");
  __builtin_amdgcn_s_barrier();
  qkt(buf1, sB);
  smpv(sA, vfA);
  ldv(buf1, vfB);
  // drain
  smpv(sB, vfB);

  // ---- split-k-2 merge (wk pairs). Tile buffers dead; reuse LDS.
  __syncthreads();  // all waves done with tile buffers
  l_run += __shfl_xor(l_run, 32);
  float* O1 = (float*)lds;
  float* L1 = (float*)(lds + 32768);
  if (wk == 1) {
#pragma unroll
    for (int dg = 0; dg < 4; ++dg)
#pragma unroll
      for (int r = 0; r < 16; ++r)
        O1[wm * 4096 + (dg * 16 + r) * 64 + l] = oacc[dg][r];
    if (l < 32) L1[wm * 32 + c31] = l_run;
  }
  __syncthreads();
  if (wk == 0) {
    float linv = 1.0f / (l_run + L1[wm * 32 + c31]);
    int ibits = __builtin_bit_cast(int, linv);
#pragma unroll
    for (int dg = 0; dg < 4; ++dg) {
      int h = dg * 32 + c31;
#pragma unroll
      for (int r = 0; r < 16; ++r) {
        int crow = (r & 3) + 8 * (r >> 2) + 4 * hi;
        float fr = __builtin_bit_cast(
            float, __builtin_amdgcn_ds_bpermute(crow * 4, ibits));
        float val = (oacc[dg][r] + O1[wm * 4096 + (dg * 16 + r) * 64 + l]) * fr;
        int n = q0 + wm * 32 + crow;
        O[((size_t)b * NDIM + n) * HDIM + h] = (bf16)val;
      }
    }
  }
}

// ---------------------------------------------------------------------------
// Kernel 3: out = Wf @ O + bf + x (frozen; ~at HBM floor)
// ---------------------------------------------------------------------------
__global__ __launch_bounds__(256) void k3_proj(
    const bf16* __restrict__ O, const float* __restrict__ Wf,
    const float* __restrict__ bfv, const float* __restrict__ x,
    float* __restrict__ out) {
  __shared__ char lds[49152];
  char* Wt = lds;
  char* Ot = lds + 32768;

  const int t = threadIdx.x;
  const int l = t & 63;
  const int w = t >> 6;
  const int b = blockIdx.x >> 5;
  const int n0 = (blockIdx.x & 31) * 64;

#pragma unroll
  for (int pass = 0; pass < 4; ++pass) {
    int n = pass * 16 + (t >> 4);
    int hq = t & 15;
    uint4 d = *reinterpret_cast<const uint4*>(
        O + (size_t)(b * NDIM + n0 + n) * HDIM + hq * 8);
    *reinterpret_cast<uint4*>(Ot + swz256(n, hq * 16)) = d;
  }

#pragma unroll 1
  for (int ch = 0; ch < 2; ++ch) {
    __syncthreads();
#pragma unroll
    for (int pass = 0; pass < 8; ++pass) {
      int cl = pass * 16 + (t >> 4);
      int hq = t & 15;
      const float* src = Wf + (size_t)(ch * 128 + cl) * HDIM + hq * 8;
      float4 v0 = *reinterpret_cast<const float4*>(src);
      float4 v1 = *reinterpret_cast<const float4*>(src + 4);
      *reinterpret_cast<bf16x8*>(Wt + swz256(cl, hq * 16)) = cvt8(v0, v1);
    }
    __syncthreads();

    f32x4 acc[2][4];
#pragma unroll
    for (int i = 0; i < 2; ++i)
#pragma unroll
      for (int j = 0; j < 4; ++j) acc[i][j] = f32x4{0.f, 0.f, 0.f, 0.f};

#pragma unroll
    for (int ks = 0; ks < 4; ++ks) {
      int cb = ks * 64 + (l >> 4) * 16;
      bf16x8 a0 = *reinterpret_cast<const bf16x8*>(
          Wt + swz256(w * 32 + (l & 15), cb));
      bf16x8 a1 = *reinterpret_cast<const bf16x8*>(
          Wt + swz256(w * 32 + 16 + (l & 15), cb));
#pragma unroll
      for (int nf = 0; nf < 4; ++nf) {
        bf16x8 bb = *reinterpret_cast<const bf16x8*>(
            Ot + swz256(nf * 16 + (l & 15), cb));
        acc[0][nf] = mfma16(a0, bb, acc[0][nf]);
        acc[1][nf] = mfma16(a1, bb, acc[1][nf]);
      }
    }

#pragma unroll
    for (int mf = 0; mf < 2; ++mf)
#pragma unroll
      for (int nf = 0; nf < 4; ++nf)
#pragma unroll
        for (int r = 0; r < 4; ++r) {
          int c = ch * 128 + w * 32 + mf * 16 + (l >> 4) * 4 + r;
          int n = n0 + nf * 16 + (l & 15);
          size_t idx = (size_t)(b * CDIM + c) * NDIM + n;
          out[idx] = acc[mf][nf][r] + bfv[c] + x[idx];
        }
  }
}

extern "C" void kernel_launch(void* const* d_in, const int* in_sizes, int n_in,
                              void* d_out, int out_size, void* d_ws,
                              size_t ws_size, hipStream_t stream) {
  (void)in_sizes; (void)n_in;
  const float* x = (const float*)d_in[0];
  const float* Wq = (const float*)d_in[1];
  const float* bq = (const float*)d_in[2];
  const float* Wk = (const float*)d_in[3];
  const float* bk = (const float*)d_in[4];
  const float* Wv = (const float*)d_in[5];
  const float* bv = (const float*)d_in[6];
  const float* Wf = (const float*)d_in[7];
  const float* bfv = (const float*)d_in[8];
  float* out = (float*)d_out;

  if (ws_size < (24u << 20)) return;
  char* ws = (char*)d_ws;
  bf16* Qb = (bf16*)(ws);                  // 8 MB [B][N][H]; reused as O
  bf16* Kb = (bf16*)(ws + (8u << 20));     // 8 MB [B][N][H]
  bf16* Vb = (bf16*)(ws + (16u << 20));    // 8 MB [B][H][N]

  const size_t out_bytes = (size_t)out_size * 4;
  bf16* Wpk = (bf16*)((char*)d_out + out_bytes - 196608);

  const unsigned k2_lds = 65536;
  hipFuncSetAttribute(reinterpret_cast<const void*>(k2_attn),
                      hipFuncAttributeMaxDynamicSharedMemorySize, (int)k2_lds);

  k0_pack<<<48, 256, 0, stream>>>(Wq, Wk, Wv, Wpk);
  k1_qkv<<<512, 256, 0, stream>>>(x, Wpk, bq, bk, bv, Qb, Kb, Vb);
  k2_attn<<<512, 256, k2_lds, stream>>>(Qb, Kb, Vb, Qb);
  k3_proj<<<512, 256, 0, stream>>>(Qb, Wf, bfv, x, out);
}